// Round 3
// baseline (1058.871 us; speedup 1.0000x reference)
//
#include <hip/hip_runtime.h>
#include <hip/hip_bf16.h>

typedef short s16x8 __attribute__((ext_vector_type(8)));
typedef unsigned short u16x4 __attribute__((ext_vector_type(4)));
typedef float f32x4 __attribute__((ext_vector_type(4)));
typedef unsigned short u16;

#define DEV static __device__ __forceinline__

#if __has_builtin(__builtin_amdgcn_exp2f)
#define EXP2F(x) __builtin_amdgcn_exp2f(x)
#else
#define EXP2F(x) exp2f(x)
#endif

constexpr int D    = 256;
constexpr int SEQ  = 4096;
constexpr int NB   = 8;
constexpr int NTOK = NB * SEQ;                 // 32768
constexpr size_t N_EMB = (size_t)NTOK * D;     // 8388608 elems
constexpr size_t N_W   = (size_t)D * D;        // 65536 elems
constexpr float SM_C = 0.09016844005556021f;   // (1/16) * log2(e)

DEV float bf2f(u16 u){ unsigned v = ((unsigned)u) << 16; float f; __builtin_memcpy(&f,&v,4); return f; }
DEV u16 f2bf(float f){ unsigned v; __builtin_memcpy(&v,&f,4); v += 0x7fffu + ((v>>16)&1u); return (u16)(v>>16); }

DEV float rmax16(float v){
  v = fmaxf(v, __shfl_xor(v,1)); v = fmaxf(v, __shfl_xor(v,2));
  v = fmaxf(v, __shfl_xor(v,4)); v = fmaxf(v, __shfl_xor(v,8));
  return v;
}
DEV float rsum16(float v){
  v += __shfl_xor(v,1); v += __shfl_xor(v,2);
  v += __shfl_xor(v,4); v += __shfl_xor(v,8);
  return v;
}

// async global->LDS, 16B per lane; lds dst = wave-uniform base + lane*16
DEV void gl2lds16(const u16* g, void* lds){
  __builtin_amdgcn_global_load_lds(
      (const __attribute__((address_space(1))) void*)g,
      (__attribute__((address_space(3))) void*)lds, 16, 0, 0);
}
// lgkmcnt(0)-only wait + raw barrier: does NOT drain vmcnt (keeps K-DMA in flight)
DEV void lgkm_barrier(){
  __builtin_amdgcn_s_waitcnt(0xC07F);   // vmcnt=63, expcnt=7, lgkmcnt=0
  __builtin_amdgcn_s_barrier();
}

// ---------------------------------------------------------------------------
// Kernel 0: f32 -> bf16 convert of TE, SE, Wq, Wk, Wv into workspace.
// ---------------------------------------------------------------------------
__global__ __launch_bounds__(256)
void cvt_all(const float* __restrict__ TE, const float* __restrict__ SE,
             const float* __restrict__ Wq, const float* __restrict__ Wk,
             const float* __restrict__ Wv, u16* __restrict__ dst)
{
  const size_t total4 = (2*N_EMB + 3*N_W) / 4;
  for (size_t i = (size_t)blockIdx.x*256 + threadIdx.x; i < total4;
       i += (size_t)gridDim.x*256) {
    size_t e = i*4;
    const float* s;
    if      (e < N_EMB)            s = TE + e;
    else if (e < 2*N_EMB)          s = SE + (e - N_EMB);
    else if (e < 2*N_EMB + N_W)    s = Wq + (e - 2*N_EMB);
    else if (e < 2*N_EMB + 2*N_W)  s = Wk + (e - 2*N_EMB - N_W);
    else                           s = Wv + (e - 2*N_EMB - 2*N_W);
    f32x4 v = *(const f32x4*)s;
    u16x4 o;
#pragma unroll
    for (int j = 0; j < 4; j++) o[j] = f2bf(v[j]);
    *(u16x4*)(dst + e) = o;
  }
}

// ---------------------------------------------------------------------------
// Kernel 1: QKV projections (bf16). mode 0: Q row-major, 1: K row-major,
//           2: V^T [b][o][s].
// ---------------------------------------------------------------------------
__global__ __launch_bounds__(256, 4)
void qkv_proj(const u16* __restrict__ TEb, const u16* __restrict__ SEb,
              const u16* __restrict__ Wqb, const float* __restrict__ bq,
              const u16* __restrict__ Wkb, const float* __restrict__ bk,
              const u16* __restrict__ Wvb, const float* __restrict__ bv,
              u16* __restrict__ Qb, u16* __restrict__ Kb, u16* __restrict__ Vt)
{
  const int mode = blockIdx.y;
  const int t0   = blockIdx.x * 64;
  const int lane = threadIdx.x & 63;
  const int wv   = threadIdx.x >> 6;
  const int li   = lane & 15, grp = lane >> 4;

  const u16*   X    = (mode == 0) ? TEb : SEb;
  const u16*   W    = (mode == 0) ? Wqb : (mode == 1) ? Wkb : Wvb;
  const float* bias = (mode == 0) ? bq  : (mode == 1) ? bk  : bv;

  if (mode < 2) {
    u16* Y = (mode == 0) ? Qb : Kb;
    const u16* xrow = X + (size_t)(t0 + 16*wv + li) * D + grp*8;
    s16x8 a[8];
#pragma unroll
    for (int ks = 0; ks < 8; ks++) a[ks] = *(const s16x8*)(xrow + ks*32);
    f32x4 acc[16];
#pragma unroll
    for (int i = 0; i < 16; i++) acc[i] = (f32x4){0.f,0.f,0.f,0.f};
#pragma unroll
    for (int nt = 0; nt < 16; nt++) {
      const u16* wrow = W + (size_t)(16*nt + li) * D + grp*8;
#pragma unroll
      for (int ks = 0; ks < 8; ks++) {
        s16x8 bf = *(const s16x8*)(wrow + ks*32);
        acc[nt] = __builtin_amdgcn_mfma_f32_16x16x32_bf16(a[ks], bf, acc[nt], 0,0,0);
      }
    }
#pragma unroll
    for (int nt = 0; nt < 16; nt++) {
      int col = li + 16*nt;
      float bb = bias[col];
#pragma unroll
      for (int r = 0; r < 4; r++) {
        int row = t0 + 16*wv + grp*4 + r;
        Y[(size_t)row*D + col] = f2bf(acc[nt][r] + bb);
      }
    }
  } else {
    f32x4 acc[16];
#pragma unroll
    for (int i = 0; i < 16; i++) acc[i] = (f32x4){0.f,0.f,0.f,0.f};
#pragma unroll
    for (int ks = 0; ks < 8; ks++) {
      s16x8 a[4], bb[4];
#pragma unroll
      for (int mt = 0; mt < 4; mt++)
        a[mt] = *(const s16x8*)(W + (size_t)(64*wv + 16*mt + li) * D + ks*32 + grp*8);
#pragma unroll
      for (int nt = 0; nt < 4; nt++)
        bb[nt] = *(const s16x8*)(X + (size_t)(t0 + 16*nt + li) * D + ks*32 + grp*8);
#pragma unroll
      for (int mt = 0; mt < 4; mt++)
#pragma unroll
        for (int nt = 0; nt < 4; nt++)
          acc[mt*4+nt] = __builtin_amdgcn_mfma_f32_16x16x32_bf16(a[mt], bb[nt], acc[mt*4+nt], 0,0,0);
    }
    const int b = t0 >> 12, s0 = t0 & (SEQ - 1);
#pragma unroll
    for (int mt = 0; mt < 4; mt++) {
#pragma unroll
      for (int r = 0; r < 4; r++) {
        int o = 64*wv + 16*mt + grp*4 + r;
        float bb = bias[o];
        u16* yrow = Vt + ((size_t)b * D + o) * SEQ + s0;
#pragma unroll
        for (int nt = 0; nt < 4; nt++)
          yrow[16*nt + li] = f2bf(acc[mt*4+nt][r] + bb);
      }
    }
  }
}

// ---------------------------------------------------------------------------
// Kernel 2: flash attention, split-K halves. Writes raw O (bf16) + (m,l).
// Block = (b, k-half h, 64-row q tile). 4 waves.
// K tile 32x256 double-buffered via global_load_lds (source-side xor swizzle);
// V frags read per-wave from global V^T; P via LDS; 2 barriers/iter
// (top = __syncthreads drains K-DMA; mid = lgkm-only raw barrier).
// ---------------------------------------------------------------------------
constexpr int KB0   = 0;         // K buf 0: 16KB
constexpr int KB1   = 16384;     // K buf 1: 16KB
constexpr int P_OFF = 32768;     // P 64x32 bf16: 4KB
constexpr int AL_OFF= 36864;     // alpha f32[64]
constexpr int LDS2  = 37120;
constexpr int NIT   = 64;        // 2048 k-cols per half / 32

__global__ __launch_bounds__(256, 4)
void attn_fa(const u16* __restrict__ Qb, const u16* __restrict__ Kb,
             const u16* __restrict__ Vt,
             u16* __restrict__ O0, u16* __restrict__ O1, float* __restrict__ ml)
{
  __shared__ __align__(16) char smem[LDS2];
  const int tid  = threadIdx.x;
  const int lane = tid & 63, wv = tid >> 6;
  const int li   = lane & 15, grp = lane >> 4;
  const int b  = blockIdx.x & 7;                  // XCD swizzle: batch -> XCD
  const int h  = (blockIdx.x >> 3) & 1;
  const int q0 = (blockIdx.x >> 4) * 64;
  u16* Op = h ? O1 : O0;

  const u16* Kbase = Kb + ((size_t)b*SEQ + h*2048) * D;
  const u16* Vbase = Vt + (size_t)b * D * SEQ + h*2048;

  // Q fragments in registers
  const u16* qrow = Qb + ((size_t)b*SEQ + q0 + 16*wv + li)*D + grp*8;
  s16x8 qf[8];
#pragma unroll
  for (int ks = 0; ks < 8; ks++) qf[ks] = *(const s16x8*)(qrow + ks*32);

  // DMA source offsets (elems). LDS slot (u=wv*4+c, lane): row r=2u+(lane>>5),
  // pos jj=lane&31 must hold global chunk jj^(r&7) of row r.
  int soff[4];
#pragma unroll
  for (int c = 0; c < 4; c++) {
    int u = wv*4 + c;
    int r = 2*u + (lane >> 5);
    soff[c] = r*256 + (((lane & 31) ^ (r & 7)) * 8);
  }
  // V frag offsets (elems, lane-fixed)
  int voff[4];
#pragma unroll
  for (int nt = 0; nt < 4; nt++) voff[nt] = (64*wv + 16*nt + li)*SEQ + grp*8;

  // prime: DMA tile 0 into KB0
#pragma unroll
  for (int c = 0; c < 4; c++)
    gl2lds16(Kbase + soff[c], smem + KB0 + (wv*4 + c)*1024);

  f32x4 oacc[16];
#pragma unroll
  for (int i = 0; i < 16; i++) oacc[i] = (f32x4){0.f,0.f,0.f,0.f};
  float m_r[4] = {-1e30f,-1e30f,-1e30f,-1e30f};
  float l_r[4] = {0.f,0.f,0.f,0.f};

  float* alpha_lds = (float*)(smem + AL_OFF);
  u16*   Pl        = (u16*)(smem + P_OFF);

  for (int it = 0; it < NIT; it++) {
    const int k0 = it * 32;
    __syncthreads();   // drains vmcnt(0): K tile `it` resident; P(it-1) consumed

    // prefetch K tile it+1 into the other buffer (in flight across this iter)
    {
      const u16* Kt = Kbase + (size_t)((it+1 < NIT) ? (k0+32) : k0) * D;
      char* kbn = smem + ((it & 1) ? KB0 : KB1);
#pragma unroll
      for (int c = 0; c < 4; c++)
        gl2lds16(Kt + soff[c], kbn + (wv*4 + c)*1024);
    }

    // S = Q K^T (wave's 16 q rows x 32 k cols) from current buffer
    const char* kb = smem + ((it & 1) ? KB1 : KB0);
    f32x4 sa0 = {0.f,0.f,0.f,0.f}, sa1 = {0.f,0.f,0.f,0.f};
    {
      const int r0 = li, r1 = li + 16;
      const char* kp0 = kb + r0*512;
      const char* kp1 = kb + r1*512;
#pragma unroll
      for (int ks = 0; ks < 8; ks++) {
        s16x8 k0f = *(const s16x8*)(kp0 + 16*((4*ks + grp) ^ (r0 & 7)));
        sa0 = __builtin_amdgcn_mfma_f32_16x16x32_bf16(qf[ks], k0f, sa0, 0,0,0);
        s16x8 k1f = *(const s16x8*)(kp1 + 16*((4*ks + grp) ^ (r1 & 7)));
        sa1 = __builtin_amdgcn_mfma_f32_16x16x32_bf16(qf[ks], k1f, sa1, 0,0,0);
      }
    }

    // online softmax
#pragma unroll
    for (int r = 0; r < 4; r++) {
      float tmax = rmax16(fmaxf(sa0[r], sa1[r]));
      float mn = fmaxf(m_r[r], tmax);
      float al = EXP2F((m_r[r] - mn) * SM_C);
      float p0 = EXP2F((sa0[r] - mn) * SM_C);
      float p1 = EXP2F((sa1[r] - mn) * SM_C);
      float rs = rsum16(p0 + p1);
      l_r[r] = l_r[r] * al + rs;
      m_r[r] = mn;
      int row = 16*wv + grp*4 + r;
      Pl[row*32 + li]      = f2bf(p0);
      Pl[row*32 + li + 16] = f2bf(p1);
      if (li == 0) alpha_lds[row] = al;
    }
    lgkm_barrier();   // P/alpha visible; K-DMA stays in flight

    // V fragments straight from global (L2-resident)
    s16x8 vf[4];
#pragma unroll
    for (int nt = 0; nt < 4; nt++)
      vf[nt] = *(const s16x8*)(Vbase + voff[nt] + k0);

    // rescale O (skip when no row max moved)
    float av[4][4];
    bool need = false;
#pragma unroll
    for (int mt = 0; mt < 4; mt++)
#pragma unroll
      for (int r = 0; r < 4; r++) {
        av[mt][r] = alpha_lds[16*mt + grp*4 + r];
        need |= (av[mt][r] < 1.0f);
      }
    if (__any(need)) {
#pragma unroll
      for (int mt = 0; mt < 4; mt++)
#pragma unroll
        for (int nt = 0; nt < 4; nt++)
#pragma unroll
          for (int r = 0; r < 4; r++)
            oacc[mt*4+nt][r] *= av[mt][r];
    }

    // O += P.V (wave's 64-col d strip)
#pragma unroll
    for (int mt = 0; mt < 4; mt++) {
      s16x8 pf = *(const s16x8*)(smem + P_OFF + (16*mt + li)*64 + grp*16);
#pragma unroll
      for (int nt = 0; nt < 4; nt++)
        oacc[mt*4+nt] = __builtin_amdgcn_mfma_f32_16x16x32_bf16(pf, vf[nt], oacc[mt*4+nt], 0,0,0);
    }
  }

  // epilogue: raw O (bf16) + per-row (m,l)
#pragma unroll
  for (int mt = 0; mt < 4; mt++) {
#pragma unroll
    for (int r = 0; r < 4; r++) {
      size_t row = (size_t)b*SEQ + q0 + 16*mt + grp*4 + r;
#pragma unroll
      for (int nt = 0; nt < 4; nt++)
        Op[row*D + 64*wv + 16*nt + li] = f2bf(oacc[mt*4+nt][r]);
    }
  }
  if (li == 0) {
#pragma unroll
    for (int r = 0; r < 4; r++) {
      size_t tok = (size_t)b*SEQ + q0 + 16*wv + grp*4 + r;
      ml[((size_t)h*NTOK + tok)*2]     = m_r[r];
      ml[((size_t)h*NTOK + tok)*2 + 1] = l_r[r];
    }
  }
}

// ---------------------------------------------------------------------------
// Kernel 3: combine the two K-halves + residual + LayerNorm (f32 out).
// Block = 64 rows; wave = 16 rows serial; lane covers 4 cols.
// ---------------------------------------------------------------------------
__global__ __launch_bounds__(256, 4)
void combine_ln(const u16* __restrict__ O0, const u16* __restrict__ O1,
                const float* __restrict__ ml, const float* __restrict__ TE,
                const float* __restrict__ gamma, const float* __restrict__ beta,
                float* __restrict__ out)
{
  const int tid = threadIdx.x, lane = tid & 63, wv = tid >> 6;
  const int base = blockIdx.x * 64 + wv * 16;
  f32x4 g4 = *(const f32x4*)(gamma + lane*4);
  f32x4 b4 = *(const f32x4*)(beta  + lane*4);
  for (int rr = 0; rr < 16; rr++) {
    const size_t tok = (size_t)base + rr;
    u16x4 a0 = *(const u16x4*)(O0 + tok*D + lane*4);
    u16x4 a1 = *(const u16x4*)(O1 + tok*D + lane*4);
    f32x4 te = *(const f32x4*)(TE + tok*D + lane*4);
    float m0 = ml[tok*2],              l0 = ml[tok*2 + 1];
    float m1 = ml[((size_t)NTOK+tok)*2], l1 = ml[((size_t)NTOK+tok)*2 + 1];
    float M  = fmaxf(m0, m1);
    float e0 = EXP2F((m0 - M) * SM_C), e1 = EXP2F((m1 - M) * SM_C);
    float inv = 1.0f / (l0*e0 + l1*e1);
    f32x4 x; float ps = 0.f, pq = 0.f;
#pragma unroll
    for (int j = 0; j < 4; j++) {
      x[j] = (bf2f(a0[j])*e0 + bf2f(a1[j])*e1) * inv + te[j];
      ps += x[j]; pq += x[j]*x[j];
    }
#pragma unroll
    for (int o = 1; o < 64; o <<= 1) { ps += __shfl_xor(ps, o); pq += __shfl_xor(pq, o); }
    float mu = ps * (1.0f/256.0f);
    float var = pq * (1.0f/256.0f) - mu*mu;
    float rstd = rsqrtf(var + 1e-5f);
    f32x4 y;
#pragma unroll
    for (int j = 0; j < 4; j++) y[j] = (x[j] - mu) * rstd * g4[j] + b4[j];
    *(f32x4*)(out + tok*D + lane*4) = y;
  }
}

// ---------------------------------------------------------------------------
extern "C" void kernel_launch(void* const* d_in, const int* in_sizes, int n_in,
                              void* d_out, int out_size, void* d_ws, size_t ws_size,
                              hipStream_t stream)
{
  (void)in_sizes; (void)n_in; (void)out_size; (void)ws_size;
  const float* SE = (const float*)d_in[0];
  const float* TE = (const float*)d_in[1];
  const float* Wq = (const float*)d_in[2];
  const float* bq = (const float*)d_in[3];
  const float* Wk = (const float*)d_in[4];
  const float* bk = (const float*)d_in[5];
  const float* Wv = (const float*)d_in[6];
  const float* bv = (const float*)d_in[7];
  const float* gm = (const float*)d_in[8];
  const float* bt = (const float*)d_in[9];

  u16* Qb  = (u16*)d_ws;              // 16MB
  u16* Kb  = Qb + N_EMB;              // 16MB
  u16* Vtr = Kb + N_EMB;              // 16MB  [b][d][s]
  u16* CVT = Vtr + N_EMB;             // TEb | SEb | Wqb | Wkb | Wvb
  u16* TEb = CVT;
  u16* SEb = TEb + N_EMB;
  u16* Wqb = SEb + N_EMB;
  u16* Wkb = Wqb + N_W;
  u16* Wvb = Wkb + N_W;
  // After qkv_proj, CVT region is dead -> alias attention partials over it.
  u16*   O0p = TEb;                   // 16MB bf16
  u16*   O1p = O0p + N_EMB;           // 16MB bf16 (over SEb)
  float* ml  = (float*)Wqb;           // 512KB (over W bufs, +128KB past)

  cvt_all<<<2048, 256, 0, stream>>>(TE, SE, Wq, Wk, Wv, CVT);
  qkv_proj<<<dim3(NTOK/64, 3), 256, 0, stream>>>(TEb, SEb, Wqb, bq, Wkb, bk, Wvb, bv, Qb, Kb, Vtr);
  attn_fa<<<dim3((SEQ/64) * NB * 2), 256, 0, stream>>>(Qb, Kb, Vtr, O0p, O1p, ml);
  combine_ln<<<dim3(NTOK/64), 256, 0, stream>>>(O0p, O1p, ml, TE, gm, bt, (float*)d_out);
}

// Round 4
// 522.803 us; speedup vs baseline: 2.0254x; 2.0254x over previous
//
#include <hip/hip_runtime.h>
#include <hip/hip_bf16.h>

typedef short s16x8 __attribute__((ext_vector_type(8)));
typedef unsigned short u16x4 __attribute__((ext_vector_type(4)));
typedef float f32x4 __attribute__((ext_vector_type(4)));
typedef unsigned short u16;

#define DEV static __device__ __forceinline__

#if __has_builtin(__builtin_amdgcn_exp2f)
#define EXP2F(x) __builtin_amdgcn_exp2f(x)
#else
#define EXP2F(x) exp2f(x)
#endif

constexpr int D    = 256;
constexpr int SEQ  = 4096;
constexpr int NB   = 8;
constexpr int NTOK = NB * SEQ;                 // 32768
constexpr size_t N_EMB = (size_t)NTOK * D;     // 8388608 elems
constexpr size_t N_W   = (size_t)D * D;        // 65536 elems
constexpr float SM_C = 0.09016844005556021f;   // (1/16) * log2(e)

DEV u16 f2bf(float f){ unsigned v; __builtin_memcpy(&v,&f,4); v += 0x7fffu + ((v>>16)&1u); return (u16)(v>>16); }

DEV float rmax16(float v){
  v = fmaxf(v, __shfl_xor(v,1)); v = fmaxf(v, __shfl_xor(v,2));
  v = fmaxf(v, __shfl_xor(v,4)); v = fmaxf(v, __shfl_xor(v,8));
  return v;
}
DEV float rsum16(float v){
  v += __shfl_xor(v,1); v += __shfl_xor(v,2);
  v += __shfl_xor(v,4); v += __shfl_xor(v,8);
  return v;
}

DEV void gl2lds16(const u16* g, void* lds){
  __builtin_amdgcn_global_load_lds(
      (const __attribute__((address_space(1))) void*)g,
      (__attribute__((address_space(3))) void*)lds, 16, 0, 0);
}
// lgkmcnt(0)-only wait + raw barrier: K-DMA (vmcnt) stays in flight
DEV void lgkm_barrier(){
  __builtin_amdgcn_s_waitcnt(0xC07F);   // vmcnt=63, expcnt=7, lgkmcnt=0
  __builtin_amdgcn_s_barrier();
}

// convert two f32x4 -> one bf16x8 fragment
DEV s16x8 cvt8(const float* p){
  f32x4 u = *(const f32x4*)p;
  f32x4 w = *(const f32x4*)(p + 4);
  s16x8 t;
#pragma unroll
  for (int j = 0; j < 4; j++){ t[j] = (short)f2bf(u[j]); t[j+4] = (short)f2bf(w[j]); }
  return t;
}

// ---------------------------------------------------------------------------
// Kernel 0: f32 -> bf16 convert of Wq|Wk|Wv only (3*65536 elems).
// ---------------------------------------------------------------------------
__global__ __launch_bounds__(256)
void cvt_w(const float* __restrict__ Wq, const float* __restrict__ Wk,
           const float* __restrict__ Wv, u16* __restrict__ dst)
{
  size_t i = ((size_t)blockIdx.x*256 + threadIdx.x) * 4;   // grid covers 3*N_W
  const float* s = (i < N_W) ? (Wq + i) : (i < 2*N_W) ? (Wk + i - N_W) : (Wv + i - 2*N_W);
  f32x4 v = *(const f32x4*)s;
  u16x4 o;
#pragma unroll
  for (int j = 0; j < 4; j++) o[j] = f2bf(v[j]);
  *(u16x4*)(dst + i) = o;
}

// ---------------------------------------------------------------------------
// Kernel 1: QKV projections, X read as f32 + in-reg cvt; W pre-cvt bf16.
// mode 0: Q = TE@Wq^T+bq (row-major), 1: K (row-major), 2: V^T [b][o][s].
// ---------------------------------------------------------------------------
__global__ __launch_bounds__(256, 2)
void qkv_proj(const float* __restrict__ TE, const float* __restrict__ SE,
              const u16* __restrict__ Wqb, const float* __restrict__ bq,
              const u16* __restrict__ Wkb, const float* __restrict__ bk,
              const u16* __restrict__ Wvb, const float* __restrict__ bv,
              u16* __restrict__ Qb, u16* __restrict__ Kb, u16* __restrict__ Vt)
{
  const int mode = blockIdx.y;
  const int t0   = blockIdx.x * 64;
  const int lane = threadIdx.x & 63;
  const int wv   = threadIdx.x >> 6;
  const int li   = lane & 15, grp = lane >> 4;

  const float* X    = (mode == 0) ? TE  : SE;
  const u16*   W    = (mode == 0) ? Wqb : (mode == 1) ? Wkb : Wvb;
  const float* bias = (mode == 0) ? bq  : (mode == 1) ? bk  : bv;

  if (mode < 2) {
    u16* Y = (mode == 0) ? Qb : Kb;
    const float* xrow = X + (size_t)(t0 + 16*wv + li) * D + grp*8;
    s16x8 a[8];
#pragma unroll
    for (int ks = 0; ks < 8; ks++) a[ks] = cvt8(xrow + ks*32);
    f32x4 acc[16];
#pragma unroll
    for (int i = 0; i < 16; i++) acc[i] = (f32x4){0.f,0.f,0.f,0.f};
#pragma unroll
    for (int nt = 0; nt < 16; nt++) {
      const u16* wrow = W + (size_t)(16*nt + li) * D + grp*8;
#pragma unroll
      for (int ks = 0; ks < 8; ks++) {
        s16x8 bf = *(const s16x8*)(wrow + ks*32);
        acc[nt] = __builtin_amdgcn_mfma_f32_16x16x32_bf16(a[ks], bf, acc[nt], 0,0,0);
      }
    }
#pragma unroll
    for (int nt = 0; nt < 16; nt++) {
      int col = li + 16*nt;
      float bb = bias[col];
#pragma unroll
      for (int r = 0; r < 4; r++) {
        int row = t0 + 16*wv + grp*4 + r;
        Y[(size_t)row*D + col] = f2bf(acc[nt][r] + bb);
      }
    }
  } else {
    f32x4 acc[16];
#pragma unroll
    for (int i = 0; i < 16; i++) acc[i] = (f32x4){0.f,0.f,0.f,0.f};
#pragma unroll
    for (int ks = 0; ks < 8; ks++) {
      s16x8 a[4], bb[4];
#pragma unroll
      for (int mt = 0; mt < 4; mt++)
        a[mt] = *(const s16x8*)(W + (size_t)(64*wv + 16*mt + li) * D + ks*32 + grp*8);
#pragma unroll
      for (int nt = 0; nt < 4; nt++)
        bb[nt] = cvt8(X + (size_t)(t0 + 16*nt + li) * D + ks*32 + grp*8);
#pragma unroll
      for (int mt = 0; mt < 4; mt++)
#pragma unroll
        for (int nt = 0; nt < 4; nt++)
          acc[mt*4+nt] = __builtin_amdgcn_mfma_f32_16x16x32_bf16(a[mt], bb[nt], acc[mt*4+nt], 0,0,0);
    }
    const int b = t0 >> 12, s0 = t0 & (SEQ - 1);
#pragma unroll
    for (int mt = 0; mt < 4; mt++) {
#pragma unroll
      for (int r = 0; r < 4; r++) {
        int o = 64*wv + 16*mt + grp*4 + r;
        float bb = bias[o];
        u16* yrow = Vt + ((size_t)b * D + o) * SEQ + s0;
#pragma unroll
        for (int nt = 0; nt < 4; nt++)
          yrow[16*nt + li] = f2bf(acc[mt*4+nt][r] + bb);
      }
    }
  }
}

// ---------------------------------------------------------------------------
// Kernel 2: fused flash attention + residual + LayerNorm.
// Block = (b, 64-row q tile), 4 waves, 2 blocks/CU (no spills).
// K tile 32x256 double-buffered via global_load_lds (source-side xor swizzle,
// prefetched 1 iter ahead); V frags prefetched from global (L2-resident);
// P in LDS, row stride 36 u16 (phase-conflict-free); 2 barriers/iter.
// ---------------------------------------------------------------------------
constexpr int KB0   = 0;         // K buf 0: 16KB
constexpr int KB1   = 16384;     // K buf 1: 16KB
constexpr int P_OFF = 32768;     // P: 64 rows x 36 u16 = 4608 B
constexpr int PSTR  = 36;
constexpr int AL_OFF= 37376;     // alpha f32[64]
constexpr int L_OFF = 37632;     // l     f32[64]
constexpr int G_OFF = 37888;     // gamma f32[256]
constexpr int BE_OFF= 38912;     // beta  f32[256]
constexpr int LDS_SZ= 39936;
constexpr int NIT   = SEQ / 32;  // 128

__global__ __launch_bounds__(256, 2)
void attn_ln(const u16* __restrict__ Qb, const u16* __restrict__ Kb,
             const u16* __restrict__ Vt, const float* __restrict__ TE,
             const float* __restrict__ gamma, const float* __restrict__ beta,
             float* __restrict__ out)
{
  __shared__ __align__(16) char smem[LDS_SZ];
  const int tid  = threadIdx.x;
  const int lane = tid & 63, wv = tid >> 6;
  const int li   = lane & 15, grp = lane >> 4;
  const int b  = blockIdx.x & 7;                  // XCD swizzle: batch -> XCD
  const int q0 = (blockIdx.x >> 3) * 64;

  float* gam = (float*)(smem + G_OFF);
  float* bet = (float*)(smem + BE_OFF);
  gam[tid] = gamma[tid];
  bet[tid] = beta[tid];

  const u16* Kbase = Kb + (size_t)b * SEQ * D;
  const u16* Vbase = Vt + (size_t)b * D * SEQ;

  // Q fragments in registers
  const u16* qrow = Qb + ((size_t)b*SEQ + q0 + 16*wv + li)*D + grp*8;
  s16x8 qf[8];
#pragma unroll
  for (int ks = 0; ks < 8; ks++) qf[ks] = *(const s16x8*)(qrow + ks*32);

  // DMA source offsets: LDS slot (u=wv*4+c, lane) holds row r=2u+(lane>>5),
  // chunk jj=lane&31 <- global chunk jj^(r&7) of row r.  (validated R3)
  int soff[4];
#pragma unroll
  for (int c = 0; c < 4; c++) {
    int u = wv*4 + c;
    int r = 2*u + (lane >> 5);
    soff[c] = r*256 + (((lane & 31) ^ (r & 7)) * 8);
  }
  int voff[4];
#pragma unroll
  for (int nt = 0; nt < 4; nt++) voff[nt] = (64*wv + 16*nt + li)*SEQ + grp*8;

  // prime: DMA tile 0 into KB0
#pragma unroll
  for (int c = 0; c < 4; c++)
    gl2lds16(Kbase + soff[c], smem + KB0 + (wv*4 + c)*1024);

  f32x4 oacc[16];
#pragma unroll
  for (int i = 0; i < 16; i++) oacc[i] = (f32x4){0.f,0.f,0.f,0.f};
  float m_r[4] = {-1e30f,-1e30f,-1e30f,-1e30f};
  float l_r[4] = {0.f,0.f,0.f,0.f};

  float* alpha_lds = (float*)(smem + AL_OFF);
  u16*   Pl        = (u16*)(smem + P_OFF);

  for (int it = 0; it < NIT; it++) {
    const int k0 = it * 32;
    __syncthreads();   // vmcnt(0) drain: tile `it` resident; P(it-1) consumed

    // prefetch K tile it+1 (DMA, in flight across this whole iter)
    {
      const u16* Kt = Kbase + (size_t)((it+1 < NIT) ? (k0+32) : k0) * D;
      char* kbn = smem + ((it & 1) ? KB0 : KB1);
#pragma unroll
      for (int c = 0; c < 4; c++)
        gl2lds16(Kt + soff[c], kbn + (wv*4 + c)*1024);
    }
    // prefetch V frags for THIS iter (used after softmax; latency hidden)
    s16x8 vf[4];
#pragma unroll
    for (int nt = 0; nt < 4; nt++)
      vf[nt] = *(const s16x8*)(Vbase + voff[nt] + k0);

    // S = Q K^T (wave's 16 q rows x 32 k cols) from current buffer
    const char* kb = smem + ((it & 1) ? KB1 : KB0);
    f32x4 sa0 = {0.f,0.f,0.f,0.f}, sa1 = {0.f,0.f,0.f,0.f};
    {
      const int r0 = li, r1 = li + 16;
      const char* kp0 = kb + r0*512;
      const char* kp1 = kb + r1*512;
#pragma unroll
      for (int ks = 0; ks < 8; ks++) {
        s16x8 k0f = *(const s16x8*)(kp0 + 16*((4*ks + grp) ^ (r0 & 7)));
        sa0 = __builtin_amdgcn_mfma_f32_16x16x32_bf16(qf[ks], k0f, sa0, 0,0,0);
        s16x8 k1f = *(const s16x8*)(kp1 + 16*((4*ks + grp) ^ (r1 & 7)));
        sa1 = __builtin_amdgcn_mfma_f32_16x16x32_bf16(qf[ks], k1f, sa1, 0,0,0);
      }
    }

    // online softmax
#pragma unroll
    for (int r = 0; r < 4; r++) {
      float tmax = rmax16(fmaxf(sa0[r], sa1[r]));
      float mn = fmaxf(m_r[r], tmax);
      float al = EXP2F((m_r[r] - mn) * SM_C);
      float p0 = EXP2F((sa0[r] - mn) * SM_C);
      float p1 = EXP2F((sa1[r] - mn) * SM_C);
      float rs = rsum16(p0 + p1);
      l_r[r] = l_r[r] * al + rs;
      m_r[r] = mn;
      int row = 16*wv + grp*4 + r;
      Pl[row*PSTR + li]      = f2bf(p0);
      Pl[row*PSTR + li + 16] = f2bf(p1);
      if (li == 0) alpha_lds[row] = al;
    }
    lgkm_barrier();   // P/alpha visible; K-DMA stays in flight

    // rescale O (skip when no row max moved)
    float av[4][4];
    bool need = false;
#pragma unroll
    for (int mt = 0; mt < 4; mt++)
#pragma unroll
      for (int r = 0; r < 4; r++) {
        av[mt][r] = alpha_lds[16*mt + grp*4 + r];
        need |= (av[mt][r] < 1.0f);
      }
    if (__any(need)) {
#pragma unroll
      for (int mt = 0; mt < 4; mt++)
#pragma unroll
        for (int nt = 0; nt < 4; nt++)
#pragma unroll
          for (int r = 0; r < 4; r++)
            oacc[mt*4+nt][r] *= av[mt][r];
    }

    // O += P.V (wave's 64-col d strip)
#pragma unroll
    for (int mt = 0; mt < 4; mt++) {
      s16x8 pf = *(const s16x8*)(smem + P_OFF + ((16*mt + li)*PSTR + grp*8)*2);
#pragma unroll
      for (int nt = 0; nt < 4; nt++)
        oacc[mt*4+nt] = __builtin_amdgcn_mfma_f32_16x16x32_bf16(pf, vf[nt], oacc[mt*4+nt], 0,0,0);
    }
  }

  // ------------- epilogue: /l, +residual (f32), LayerNorm, f32 store -------------
  float* l_lds = (float*)(smem + L_OFF);
  if (li == 0) {
#pragma unroll
    for (int r = 0; r < 4; r++) l_lds[16*wv + grp*4 + r] = l_r[r];
  }
  __syncthreads();   // also: all P reads done -> P region reusable for partials

  const float* Tg = TE + ((size_t)b*SEQ + q0) * D;
  float s1[4][4], s2[4][4];
#pragma unroll
  for (int mt = 0; mt < 4; mt++) {
#pragma unroll
    for (int r = 0; r < 4; r++) {
      int row = 16*mt + grp*4 + r;
      float linv = 1.0f / l_lds[row];
      float ps = 0.f, pq = 0.f;
#pragma unroll
      for (int nt = 0; nt < 4; nt++) {
        int d_ = 64*wv + 16*nt + li;
        float x = oacc[mt*4+nt][r] * linv + Tg[(size_t)row*D + d_];
        oacc[mt*4+nt][r] = x;
        ps += x; pq += x * x;
      }
      s1[mt][r] = rsum16(ps);
      s2[mt][r] = rsum16(pq);
    }
  }
  float* part1 = (float*)(smem + P_OFF);         // [64][4] per-wave partials
  float* part2 = (float*)(smem + P_OFF + 1024);
  if (li == 0) {
#pragma unroll
    for (int mt = 0; mt < 4; mt++)
#pragma unroll
      for (int r = 0; r < 4; r++) {
        int row = 16*mt + grp*4 + r;
        part1[row*4 + wv] = s1[mt][r];
        part2[row*4 + wv] = s2[mt][r];
      }
  }
  __syncthreads();
#pragma unroll
  for (int mt = 0; mt < 4; mt++) {
#pragma unroll
    for (int r = 0; r < 4; r++) {
      int row = 16*mt + grp*4 + r;
      float su = part1[row*4+0] + part1[row*4+1] + part1[row*4+2] + part1[row*4+3];
      float sq = part2[row*4+0] + part2[row*4+1] + part2[row*4+2] + part2[row*4+3];
      float mu  = su * (1.0f/256.0f);
      float var = sq * (1.0f/256.0f) - mu*mu;
      float rstd = rsqrtf(var + 1e-5f);
      float* orow = out + ((size_t)b*SEQ + q0 + row) * D;
#pragma unroll
      for (int nt = 0; nt < 4; nt++) {
        int d_ = 64*wv + 16*nt + li;
        orow[d_] = (oacc[mt*4+nt][r] - mu) * rstd * gam[d_] + bet[d_];
      }
    }
  }
}

// ---------------------------------------------------------------------------
extern "C" void kernel_launch(void* const* d_in, const int* in_sizes, int n_in,
                              void* d_out, int out_size, void* d_ws, size_t ws_size,
                              hipStream_t stream)
{
  (void)in_sizes; (void)n_in; (void)out_size; (void)ws_size;
  const float* SE = (const float*)d_in[0];
  const float* TE = (const float*)d_in[1];
  const float* Wq = (const float*)d_in[2];
  const float* bq = (const float*)d_in[3];
  const float* Wk = (const float*)d_in[4];
  const float* bk = (const float*)d_in[5];
  const float* Wv = (const float*)d_in[6];
  const float* bv = (const float*)d_in[7];
  const float* gm = (const float*)d_in[8];
  const float* bt = (const float*)d_in[9];

  u16* Qb  = (u16*)d_ws;              // 16MB
  u16* Kb  = Qb + N_EMB;              // 16MB
  u16* Vtr = Kb + N_EMB;              // 16MB  [b][d][s]
  u16* Wqb = Vtr + N_EMB;             // 3 x 128KB bf16 weights
  u16* Wkb = Wqb + N_W;
  u16* Wvb = Wkb + N_W;

  cvt_w<<<dim3(3*N_W/1024), 256, 0, stream>>>(Wq, Wk, Wv, Wqb);
  qkv_proj<<<dim3(NTOK/64, 3), 256, 0, stream>>>(TE, SE, Wqb, bq, Wkb, bk, Wvb, bv, Qb, Kb, Vtr);
  attn_ln<<<dim3((SEQ/64) * NB), 256, 0, stream>>>(Qb, Kb, Vtr, TE, gm, bt, (float*)d_out);
}

// Round 5
// 368.184 us; speedup vs baseline: 2.8759x; 1.4199x over previous
//
#include <hip/hip_runtime.h>
#include <hip/hip_bf16.h>

typedef short s16x8 __attribute__((ext_vector_type(8)));
typedef unsigned short u16x4 __attribute__((ext_vector_type(4)));
typedef float f32x4 __attribute__((ext_vector_type(4)));
typedef unsigned short u16;

#define DEV static __device__ __forceinline__

#if __has_builtin(__builtin_amdgcn_exp2f)
#define EXP2F(x) __builtin_amdgcn_exp2f(x)
#else
#define EXP2F(x) exp2f(x)
#endif

constexpr int D    = 256;
constexpr int SEQ  = 4096;
constexpr int NB   = 8;
constexpr int NTOK = NB * SEQ;                 // 32768
constexpr size_t N_EMB = (size_t)NTOK * D;     // 8388608 elems
constexpr size_t N_W   = (size_t)D * D;        // 65536 elems
constexpr float SM_C = 0.09016844005556021f;   // (1/16) * log2(e)
// Fixed softmax max (raw-dot units). Raw scores ~ N(0,16^2); 128 = 8 sigma.
// exp2((s-128)*SM_C) can't overflow; normalization by 1/l is exact.
constexpr float SMAX = 128.0f;

DEV u16 f2bf(float f){ unsigned v; __builtin_memcpy(&v,&f,4); v += 0x7fffu + ((v>>16)&1u); return (u16)(v>>16); }

DEV float rsum16(float v){
  v += __shfl_xor(v,1); v += __shfl_xor(v,2);
  v += __shfl_xor(v,4); v += __shfl_xor(v,8);
  return v;
}

DEV void gl2lds16(const u16* g, void* lds){
  __builtin_amdgcn_global_load_lds(
      (const __attribute__((address_space(1))) void*)g,
      (__attribute__((address_space(3))) void*)lds, 16, 0, 0);
}
// lgkmcnt(0)-only wait + raw barrier: K-DMA (vmcnt) stays in flight
DEV void lgkm_barrier(){
  __builtin_amdgcn_s_waitcnt(0xC07F);   // vmcnt=63, expcnt=7, lgkmcnt=0
  __builtin_amdgcn_s_barrier();
}

// convert two f32x4 -> one bf16x8 fragment
DEV s16x8 cvt8(const float* p){
  f32x4 u = *(const f32x4*)p;
  f32x4 w = *(const f32x4*)(p + 4);
  s16x8 t;
#pragma unroll
  for (int j = 0; j < 4; j++){ t[j] = (short)f2bf(u[j]); t[j+4] = (short)f2bf(w[j]); }
  return t;
}

// ---------------------------------------------------------------------------
// Kernel 0: f32 -> bf16 convert of Wq|Wk|Wv only (3*65536 elems).
// ---------------------------------------------------------------------------
__global__ __launch_bounds__(256)
void cvt_w(const float* __restrict__ Wq, const float* __restrict__ Wk,
           const float* __restrict__ Wv, u16* __restrict__ dst)
{
  size_t i = ((size_t)blockIdx.x*256 + threadIdx.x) * 4;   // grid covers 3*N_W
  const float* s = (i < N_W) ? (Wq + i) : (i < 2*N_W) ? (Wk + i - N_W) : (Wv + i - 2*N_W);
  f32x4 v = *(const f32x4*)s;
  u16x4 o;
#pragma unroll
  for (int j = 0; j < 4; j++) o[j] = f2bf(v[j]);
  *(u16x4*)(dst + i) = o;
}

// ---------------------------------------------------------------------------
// Kernel 1: QKV projections, X read as f32 + in-reg cvt; W pre-cvt bf16.
// mode 0: Q = TE@Wq^T+bq (row-major), 1: K (row-major), 2: V^T [b][o][s].
// ---------------------------------------------------------------------------
__global__ __launch_bounds__(256, 2)
void qkv_proj(const float* __restrict__ TE, const float* __restrict__ SE,
              const u16* __restrict__ Wqb, const float* __restrict__ bq,
              const u16* __restrict__ Wkb, const float* __restrict__ bk,
              const u16* __restrict__ Wvb, const float* __restrict__ bv,
              u16* __restrict__ Qb, u16* __restrict__ Kb, u16* __restrict__ Vt)
{
  const int mode = blockIdx.y;
  const int t0   = blockIdx.x * 64;
  const int lane = threadIdx.x & 63;
  const int wv   = threadIdx.x >> 6;
  const int li   = lane & 15, grp = lane >> 4;

  const float* X    = (mode == 0) ? TE  : SE;
  const u16*   W    = (mode == 0) ? Wqb : (mode == 1) ? Wkb : Wvb;
  const float* bias = (mode == 0) ? bq  : (mode == 1) ? bk  : bv;

  if (mode < 2) {
    u16* Y = (mode == 0) ? Qb : Kb;
    const float* xrow = X + (size_t)(t0 + 16*wv + li) * D + grp*8;
    s16x8 a[8];
#pragma unroll
    for (int ks = 0; ks < 8; ks++) a[ks] = cvt8(xrow + ks*32);
    f32x4 acc[16];
#pragma unroll
    for (int i = 0; i < 16; i++) acc[i] = (f32x4){0.f,0.f,0.f,0.f};
#pragma unroll
    for (int nt = 0; nt < 16; nt++) {
      const u16* wrow = W + (size_t)(16*nt + li) * D + grp*8;
#pragma unroll
      for (int ks = 0; ks < 8; ks++) {
        s16x8 bf = *(const s16x8*)(wrow + ks*32);
        acc[nt] = __builtin_amdgcn_mfma_f32_16x16x32_bf16(a[ks], bf, acc[nt], 0,0,0);
      }
    }
#pragma unroll
    for (int nt = 0; nt < 16; nt++) {
      int col = li + 16*nt;
      float bb = bias[col];
#pragma unroll
      for (int r = 0; r < 4; r++) {
        int row = t0 + 16*wv + grp*4 + r;
        Y[(size_t)row*D + col] = f2bf(acc[nt][r] + bb);
      }
    }
  } else {
    f32x4 acc[16];
#pragma unroll
    for (int i = 0; i < 16; i++) acc[i] = (f32x4){0.f,0.f,0.f,0.f};
#pragma unroll
    for (int ks = 0; ks < 8; ks++) {
      s16x8 a[4], bb[4];
#pragma unroll
      for (int mt = 0; mt < 4; mt++)
        a[mt] = *(const s16x8*)(W + (size_t)(64*wv + 16*mt + li) * D + ks*32 + grp*8);
#pragma unroll
      for (int nt = 0; nt < 4; nt++)
        bb[nt] = cvt8(X + (size_t)(t0 + 16*nt + li) * D + ks*32 + grp*8);
#pragma unroll
      for (int mt = 0; mt < 4; mt++)
#pragma unroll
        for (int nt = 0; nt < 4; nt++)
          acc[mt*4+nt] = __builtin_amdgcn_mfma_f32_16x16x32_bf16(a[mt], bb[nt], acc[mt*4+nt], 0,0,0);
    }
    const int b = t0 >> 12, s0 = t0 & (SEQ - 1);
#pragma unroll
    for (int mt = 0; mt < 4; mt++) {
#pragma unroll
      for (int r = 0; r < 4; r++) {
        int o = 64*wv + 16*mt + grp*4 + r;
        float bb = bias[o];
        u16* yrow = Vt + ((size_t)b * D + o) * SEQ + s0;
#pragma unroll
        for (int nt = 0; nt < 4; nt++)
          yrow[16*nt + li] = f2bf(acc[mt*4+nt][r] + bb);
      }
    }
  }
}

// ---------------------------------------------------------------------------
// Kernel 2: fused flash attention (fixed-max softmax) + residual + LayerNorm.
// Block = (b, 64-row q tile), 4 waves, 2 blocks/CU.
// Per iter chain: QK -> exp2 -> P write -> lgkm barrier -> PV. No running max,
// no rescale, no in-loop reductions; l is per-lane, reduced once at the end.
// ---------------------------------------------------------------------------
constexpr int KB0   = 0;         // K buf 0: 16KB
constexpr int KB1   = 16384;     // K buf 1: 16KB
constexpr int P_OFF = 32768;     // P: 64 rows x 36 u16 = 4608 B
constexpr int PSTR  = 36;
constexpr int L_OFF = 37376;     // l     f32[64]
constexpr int G_OFF = 37632;     // gamma f32[256]
constexpr int BE_OFF= 38656;     // beta  f32[256]
constexpr int LDS_SZ= 39680;
constexpr int NIT   = SEQ / 32;  // 128

__global__ __launch_bounds__(256, 2)
void attn_ln(const u16* __restrict__ Qb, const u16* __restrict__ Kb,
             const u16* __restrict__ Vt, const float* __restrict__ TE,
             const float* __restrict__ gamma, const float* __restrict__ beta,
             float* __restrict__ out)
{
  __shared__ __align__(16) char smem[LDS_SZ];
  const int tid  = threadIdx.x;
  const int lane = tid & 63, wv = tid >> 6;
  const int li   = lane & 15, grp = lane >> 4;
  const int b  = blockIdx.x & 7;                  // XCD swizzle: batch -> XCD
  const int q0 = (blockIdx.x >> 3) * 64;

  float* gam = (float*)(smem + G_OFF);
  float* bet = (float*)(smem + BE_OFF);
  gam[tid] = gamma[tid];
  bet[tid] = beta[tid];

  const u16* Kbase = Kb + (size_t)b * SEQ * D;
  const u16* Vbase = Vt + (size_t)b * D * SEQ;

  // Q fragments in registers
  const u16* qrow = Qb + ((size_t)b*SEQ + q0 + 16*wv + li)*D + grp*8;
  s16x8 qf[8];
#pragma unroll
  for (int ks = 0; ks < 8; ks++) qf[ks] = *(const s16x8*)(qrow + ks*32);

  // DMA source offsets: LDS slot (u=wv*4+c, lane) holds row r=2u+(lane>>5),
  // chunk jj=lane&31 <- global chunk jj^(r&7) of row r.  (validated R3/R4)
  int soff[4];
#pragma unroll
  for (int c = 0; c < 4; c++) {
    int u = wv*4 + c;
    int r = 2*u + (lane >> 5);
    soff[c] = r*256 + (((lane & 31) ^ (r & 7)) * 8);
  }
  int voff[4];
#pragma unroll
  for (int nt = 0; nt < 4; nt++) voff[nt] = (64*wv + 16*nt + li)*SEQ + grp*8;

  // prime: DMA tile 0 into KB0
#pragma unroll
  for (int c = 0; c < 4; c++)
    gl2lds16(Kbase + soff[c], smem + KB0 + (wv*4 + c)*1024);

  f32x4 oacc[16];
#pragma unroll
  for (int i = 0; i < 16; i++) oacc[i] = (f32x4){0.f,0.f,0.f,0.f};
  float l_r[4] = {0.f,0.f,0.f,0.f};   // per-lane partial sums of p

  u16* Pl = (u16*)(smem + P_OFF);

  for (int it = 0; it < NIT; it++) {
    const int k0 = it * 32;
    __syncthreads();   // vmcnt(0) drain: tile `it` resident; P(it-1) consumed

    // prefetch K tile it+1 (DMA, in flight across this whole iter)
    {
      const u16* Kt = Kbase + (size_t)((it+1 < NIT) ? (k0+32) : k0) * D;
      char* kbn = smem + ((it & 1) ? KB0 : KB1);
#pragma unroll
      for (int c = 0; c < 4; c++)
        gl2lds16(Kt + soff[c], kbn + (wv*4 + c)*1024);
    }
    // prefetch V frags for THIS iter (used after the mid barrier)
    s16x8 vf[4];
#pragma unroll
    for (int nt = 0; nt < 4; nt++)
      vf[nt] = *(const s16x8*)(Vbase + voff[nt] + k0);

    // S = Q K^T (wave's 16 q rows x 32 k cols) from current buffer
    const char* kb = smem + ((it & 1) ? KB1 : KB0);
    f32x4 sa0 = {0.f,0.f,0.f,0.f}, sa1 = {0.f,0.f,0.f,0.f};
    {
      const int r0 = li, r1 = li + 16;
      const char* kp0 = kb + r0*512;
      const char* kp1 = kb + r1*512;
#pragma unroll
      for (int ks = 0; ks < 8; ks++) {
        s16x8 k0f = *(const s16x8*)(kp0 + 16*((4*ks + grp) ^ (r0 & 7)));
        sa0 = __builtin_amdgcn_mfma_f32_16x16x32_bf16(qf[ks], k0f, sa0, 0,0,0);
        s16x8 k1f = *(const s16x8*)(kp1 + 16*((4*ks + grp) ^ (r1 & 7)));
        sa1 = __builtin_amdgcn_mfma_f32_16x16x32_bf16(qf[ks], k1f, sa1, 0,0,0);
      }
    }

    // fixed-max softmax numerator: p = 2^((s - SMAX)*SM_C); no reductions
#pragma unroll
    for (int r = 0; r < 4; r++) {
      float p0 = EXP2F((sa0[r] - SMAX) * SM_C);
      float p1 = EXP2F((sa1[r] - SMAX) * SM_C);
      l_r[r] += p0 + p1;
      int row = 16*wv + grp*4 + r;
      Pl[row*PSTR + li]      = f2bf(p0);
      Pl[row*PSTR + li + 16] = f2bf(p1);
    }
    lgkm_barrier();   // P visible to all waves; K-DMA stays in flight

    // O += P.V (wave's 64-col d strip)
#pragma unroll
    for (int mt = 0; mt < 4; mt++) {
      s16x8 pf = *(const s16x8*)(smem + P_OFF + ((16*mt + li)*PSTR + grp*8)*2);
#pragma unroll
      for (int nt = 0; nt < 4; nt++)
        oacc[mt*4+nt] = __builtin_amdgcn_mfma_f32_16x16x32_bf16(pf, vf[nt], oacc[mt*4+nt], 0,0,0);
    }
  }

  // ------------- epilogue: /l, +residual (f32), LayerNorm, f32 store -------------
  float* l_lds = (float*)(smem + L_OFF);
  {
#pragma unroll
    for (int r = 0; r < 4; r++) {
      float lt = rsum16(l_r[r]);
      if (li == 0) l_lds[16*wv + grp*4 + r] = lt;
    }
  }
  __syncthreads();   // also: all P reads done -> P region reusable for partials

  const float* Tg = TE + ((size_t)b*SEQ + q0) * D;
  float s1[4][4], s2[4][4];
#pragma unroll
  for (int mt = 0; mt < 4; mt++) {
#pragma unroll
    for (int r = 0; r < 4; r++) {
      int row = 16*mt + grp*4 + r;
      float linv = 1.0f / l_lds[row];
      float ps = 0.f, pq = 0.f;
#pragma unroll
      for (int nt = 0; nt < 4; nt++) {
        int d_ = 64*wv + 16*nt + li;
        float x = oacc[mt*4+nt][r] * linv + Tg[(size_t)row*D + d_];
        oacc[mt*4+nt][r] = x;
        ps += x; pq += x * x;
      }
      s1[mt][r] = rsum16(ps);
      s2[mt][r] = rsum16(pq);
    }
  }
  float* part1 = (float*)(smem + P_OFF);         // [64][4] per-wave partials
  float* part2 = (float*)(smem + P_OFF + 1024);
  if (li == 0) {
#pragma unroll
    for (int mt = 0; mt < 4; mt++)
#pragma unroll
      for (int r = 0; r < 4; r++) {
        int row = 16*mt + grp*4 + r;
        part1[row*4 + wv] = s1[mt][r];
        part2[row*4 + wv] = s2[mt][r];
      }
  }
  __syncthreads();
#pragma unroll
  for (int mt = 0; mt < 4; mt++) {
#pragma unroll
    for (int r = 0; r < 4; r++) {
      int row = 16*mt + grp*4 + r;
      float su = part1[row*4+0] + part1[row*4+1] + part1[row*4+2] + part1[row*4+3];
      float sq = part2[row*4+0] + part2[row*4+1] + part2[row*4+2] + part2[row*4+3];
      float mu  = su * (1.0f/256.0f);
      float var = sq * (1.0f/256.0f) - mu*mu;
      float rstd = rsqrtf(var + 1e-5f);
      float* orow = out + ((size_t)b*SEQ + q0 + row) * D;
#pragma unroll
      for (int nt = 0; nt < 4; nt++) {
        int d_ = 64*wv + 16*nt + li;
        orow[d_] = (oacc[mt*4+nt][r] - mu) * rstd * gam[d_] + bet[d_];
      }
    }
  }
}

// ---------------------------------------------------------------------------
extern "C" void kernel_launch(void* const* d_in, const int* in_sizes, int n_in,
                              void* d_out, int out_size, void* d_ws, size_t ws_size,
                              hipStream_t stream)
{
  (void)in_sizes; (void)n_in; (void)out_size; (void)ws_size;
  const float* SE = (const float*)d_in[0];
  const float* TE = (const float*)d_in[1];
  const float* Wq = (const float*)d_in[2];
  const float* bq = (const float*)d_in[3];
  const float* Wk = (const float*)d_in[4];
  const float* bk = (const float*)d_in[5];
  const float* Wv = (const float*)d_in[6];
  const float* bv = (const float*)d_in[7];
  const float* gm = (const float*)d_in[8];
  const float* bt = (const float*)d_in[9];

  u16* Qb  = (u16*)d_ws;              // 16MB
  u16* Kb  = Qb + N_EMB;              // 16MB
  u16* Vtr = Kb + N_EMB;              // 16MB  [b][d][s]
  u16* Wqb = Vtr + N_EMB;             // 3 x 128KB bf16 weights
  u16* Wkb = Wqb + N_W;
  u16* Wvb = Wkb + N_W;

  cvt_w<<<dim3(3*N_W/1024), 256, 0, stream>>>(Wq, Wk, Wv, Wqb);
  qkv_proj<<<dim3(NTOK/64, 3), 256, 0, stream>>>(TE, SE, Wqb, bq, Wkb, bk, Wvb, bv, Qb, Kb, Vtr);
  attn_ln<<<dim3((SEQ/64) * NB), 256, 0, stream>>>(Qb, Kb, Vtr, TE, gm, bt, (float*)d_out);
}

// Round 6
// 340.088 us; speedup vs baseline: 3.1135x; 1.0826x over previous
//
#include <hip/hip_runtime.h>
#include <hip/hip_bf16.h>

typedef short s16x8 __attribute__((ext_vector_type(8)));
typedef unsigned short u16x4 __attribute__((ext_vector_type(4)));
typedef float f32x4 __attribute__((ext_vector_type(4)));
typedef unsigned short u16;

#define DEV static __device__ __forceinline__

#if __has_builtin(__builtin_amdgcn_exp2f)
#define EXP2F(x) __builtin_amdgcn_exp2f(x)
#else
#define EXP2F(x) exp2f(x)
#endif

constexpr int D    = 256;
constexpr int SEQ  = 4096;
constexpr int NB   = 8;
constexpr int NTOK = NB * SEQ;                 // 32768
constexpr size_t N_EMB = (size_t)NTOK * D;     // 8388608 elems
constexpr size_t N_W   = (size_t)D * D;        // 65536 elems
constexpr float SM_C = 0.09016844005556021f;   // (1/16) * log2(e)
// Fixed softmax max (raw-dot units). Raw scores ~ N(0,16^2); 128 = 8 sigma.
constexpr float SMAX = 128.0f;

DEV u16 f2bf(float f){ unsigned v; __builtin_memcpy(&v,&f,4); v += 0x7fffu + ((v>>16)&1u); return (u16)(v>>16); }

DEV float rsum16(float v){
  v += __shfl_xor(v,1); v += __shfl_xor(v,2);
  v += __shfl_xor(v,4); v += __shfl_xor(v,8);
  return v;
}

DEV void gl2lds16(const u16* g, void* lds){
  __builtin_amdgcn_global_load_lds(
      (const __attribute__((address_space(1))) void*)g,
      (__attribute__((address_space(3))) void*)lds, 16, 0, 0);
}
// lgkmcnt(0)-only wait + raw barrier: K-DMA (vmcnt) stays in flight
DEV void lgkm_barrier(){
  __builtin_amdgcn_s_waitcnt(0xC07F);   // vmcnt=63, expcnt=7, lgkmcnt=0
  __builtin_amdgcn_s_barrier();
}

// ---------------------------------------------------------------------------
// Kernel 0: f32 -> bf16 convert of TE | SE | Wq | Wk | Wv into workspace.
// ---------------------------------------------------------------------------
__global__ __launch_bounds__(256)
void cvt_all(const float* __restrict__ TE, const float* __restrict__ SE,
             const float* __restrict__ Wq, const float* __restrict__ Wk,
             const float* __restrict__ Wv, u16* __restrict__ dst)
{
  const size_t total4 = (2*N_EMB + 3*N_W) / 4;
  for (size_t i = (size_t)blockIdx.x*256 + threadIdx.x; i < total4;
       i += (size_t)gridDim.x*256) {
    size_t e = i*4;
    const float* s;
    if      (e < N_EMB)            s = TE + e;
    else if (e < 2*N_EMB)          s = SE + (e - N_EMB);
    else if (e < 2*N_EMB + N_W)    s = Wq + (e - 2*N_EMB);
    else if (e < 2*N_EMB + 2*N_W)  s = Wk + (e - 2*N_EMB - N_W);
    else                           s = Wv + (e - 2*N_EMB - 2*N_W);
    f32x4 v = *(const f32x4*)s;
    u16x4 o;
#pragma unroll
    for (int j = 0; j < 4; j++) o[j] = f2bf(v[j]);
    *(u16x4*)(dst + e) = o;
  }
}

// ---------------------------------------------------------------------------
// Kernel 1: QKV projections with W strip staged in LDS.
// Block = (mode, 64-output strip, 512-token tile). 4 waves.
// W strip 64x256 bf16 = 32 KB LDS, xor-swizzled chunks (K-tile pattern).
// Per wave per sub-iter: 64 tokens x 64 outs, MFMA:ds_read = 4:1.
// mode 0: Q = TE@Wq^T+bq (row-major), 1: K = SE@Wk^T+bk, 2: V^T [b][o][s].
// ---------------------------------------------------------------------------
__global__ __launch_bounds__(256, 3)
void qkv_proj(const u16* __restrict__ TEb, const u16* __restrict__ SEb,
              const u16* __restrict__ Wqb, const float* __restrict__ bq,
              const u16* __restrict__ Wkb, const float* __restrict__ bk,
              const u16* __restrict__ Wvb, const float* __restrict__ bv,
              u16* __restrict__ Qb, u16* __restrict__ Kb, u16* __restrict__ Vt)
{
  __shared__ __align__(16) char wlds[32768];
  const int tid  = threadIdx.x;
  const int lane = tid & 63, wv = tid >> 6;
  const int li   = lane & 15, grp = lane >> 4;
  const int mode  = blockIdx.y >> 2;
  const int strip = blockIdx.y & 3;
  const int o0    = strip * 64;
  const int tbase = blockIdx.x * 512;

  const u16*   X    = (mode == 0) ? TEb : SEb;
  const u16*   W    = (mode == 0) ? Wqb : (mode == 1) ? Wkb : Wvb;
  const float* bias = (mode == 0) ? bq  : (mode == 1) ? bk  : bv;

  // stage W strip: row r (512B), chunk jj stored at jj^(r&7)
#pragma unroll
  for (int c = 0; c < 8; c++) {
    int g = tid + 256*c;             // 2048 chunks
    int r = g >> 5, jj = g & 31;
    *(s16x8*)(wlds + r*512 + 16*(jj ^ (r & 7))) =
        *(const s16x8*)(W + (size_t)(o0 + r)*D + jj*8);
  }
  __syncthreads();

#pragma unroll 1
  for (int tt = 0; tt < 2; tt++) {
    const int base = tbase + tt*256 + wv*64;
    f32x4 acc[16];
#pragma unroll
    for (int i = 0; i < 16; i++) acc[i] = (f32x4){0.f,0.f,0.f,0.f};

    if (mode < 2) {
      // A = X tokens (global), B = W strip (LDS)
#pragma unroll
      for (int ks = 0; ks < 8; ks++) {
        s16x8 a[4], bw[4];
#pragma unroll
        for (int mt = 0; mt < 4; mt++)
          a[mt] = *(const s16x8*)(X + (size_t)(base + 16*mt + li)*D + ks*32 + grp*8);
#pragma unroll
        for (int nt = 0; nt < 4; nt++) {
          int r = 16*nt + li;
          bw[nt] = *(const s16x8*)(wlds + r*512 + 16*((4*ks + grp) ^ (r & 7)));
        }
#pragma unroll
        for (int mt = 0; mt < 4; mt++)
#pragma unroll
          for (int nt = 0; nt < 4; nt++)
            acc[mt*4+nt] = __builtin_amdgcn_mfma_f32_16x16x32_bf16(a[mt], bw[nt], acc[mt*4+nt], 0,0,0);
      }
      u16* Y = (mode == 0) ? Qb : Kb;
#pragma unroll
      for (int nt = 0; nt < 4; nt++) {
        int col = o0 + 16*nt + li;
        float bb = bias[col];
#pragma unroll
        for (int mt = 0; mt < 4; mt++)
#pragma unroll
          for (int r = 0; r < 4; r++)
            Y[(size_t)(base + 16*mt + grp*4 + r)*D + col] = f2bf(acc[mt*4+nt][r] + bb);
      }
    } else {
      // A = W strip (LDS), B = X tokens (global)  ->  D[o][token]
#pragma unroll
      for (int ks = 0; ks < 8; ks++) {
        s16x8 aw[4], bx[4];
#pragma unroll
        for (int at = 0; at < 4; at++) {
          int r = 16*at + li;
          aw[at] = *(const s16x8*)(wlds + r*512 + 16*((4*ks + grp) ^ (r & 7)));
        }
#pragma unroll
        for (int bt = 0; bt < 4; bt++)
          bx[bt] = *(const s16x8*)(X + (size_t)(base + 16*bt + li)*D + ks*32 + grp*8);
#pragma unroll
        for (int at = 0; at < 4; at++)
#pragma unroll
          for (int bt = 0; bt < 4; bt++)
            acc[at*4+bt] = __builtin_amdgcn_mfma_f32_16x16x32_bf16(aw[at], bx[bt], acc[at*4+bt], 0,0,0);
      }
      const int b = base >> 12, s0 = base & (SEQ - 1);
#pragma unroll
      for (int at = 0; at < 4; at++) {
#pragma unroll
        for (int r = 0; r < 4; r++) {
          int o = o0 + 16*at + grp*4 + r;
          float bb = bias[o];
          u16* yrow = Vt + ((size_t)b*D + o)*SEQ + s0;
#pragma unroll
          for (int bt = 0; bt < 4; bt++)
            yrow[16*bt + li] = f2bf(acc[at*4+bt][r] + bb);
        }
      }
    }
  }
}

// ---------------------------------------------------------------------------
// Kernel 2: fused flash attention (fixed-max softmax) + residual + LayerNorm.
// Block = (b, 64-row q tile), 4 waves, 3 blocks/CU.
// ---------------------------------------------------------------------------
constexpr int KB0   = 0;         // K buf 0: 16KB
constexpr int KB1   = 16384;     // K buf 1: 16KB
constexpr int P_OFF = 32768;     // P: 64 rows x 36 u16 = 4608 B
constexpr int PSTR  = 36;
constexpr int L_OFF = 37376;     // l     f32[64]
constexpr int G_OFF = 37632;     // gamma f32[256]
constexpr int BE_OFF= 38656;     // beta  f32[256]
constexpr int LDS_SZ= 39680;
constexpr int NIT   = SEQ / 32;  // 128

__global__ __launch_bounds__(256, 3)
void attn_ln(const u16* __restrict__ Qb, const u16* __restrict__ Kb,
             const u16* __restrict__ Vt, const float* __restrict__ TE,
             const float* __restrict__ gamma, const float* __restrict__ beta,
             float* __restrict__ out)
{
  __shared__ __align__(16) char smem[LDS_SZ];
  const int tid  = threadIdx.x;
  const int lane = tid & 63, wv = tid >> 6;
  const int li   = lane & 15, grp = lane >> 4;
  const int b  = blockIdx.x & 7;                  // XCD swizzle: batch -> XCD
  const int q0 = (blockIdx.x >> 3) * 64;

  float* gam = (float*)(smem + G_OFF);
  float* bet = (float*)(smem + BE_OFF);
  gam[tid] = gamma[tid];
  bet[tid] = beta[tid];

  const u16* Kbase = Kb + (size_t)b * SEQ * D;
  const u16* Vbase = Vt + (size_t)b * D * SEQ;

  // Q fragments in registers
  const u16* qrow = Qb + ((size_t)b*SEQ + q0 + 16*wv + li)*D + grp*8;
  s16x8 qf[8];
#pragma unroll
  for (int ks = 0; ks < 8; ks++) qf[ks] = *(const s16x8*)(qrow + ks*32);

  // DMA source offsets: LDS slot (u=wv*4+c, lane) holds row r=2u+(lane>>5),
  // chunk jj=lane&31 <- global chunk jj^(r&7) of row r.
  int soff[4];
#pragma unroll
  for (int c = 0; c < 4; c++) {
    int u = wv*4 + c;
    int r = 2*u + (lane >> 5);
    soff[c] = r*256 + (((lane & 31) ^ (r & 7)) * 8);
  }
  int voff[4];
#pragma unroll
  for (int nt = 0; nt < 4; nt++) voff[nt] = (64*wv + 16*nt + li)*SEQ + grp*8;

  // prime: DMA tile 0 into KB0
#pragma unroll
  for (int c = 0; c < 4; c++)
    gl2lds16(Kbase + soff[c], smem + KB0 + (wv*4 + c)*1024);

  f32x4 oacc[16];
#pragma unroll
  for (int i = 0; i < 16; i++) oacc[i] = (f32x4){0.f,0.f,0.f,0.f};
  float l_r[4] = {0.f,0.f,0.f,0.f};   // per-lane partial sums of p

  u16* Pl = (u16*)(smem + P_OFF);

  for (int it = 0; it < NIT; it++) {
    const int k0 = it * 32;
    __syncthreads();   // vmcnt(0) drain: tile `it` resident; P(it-1) consumed

    // prefetch K tile it+1 (DMA, in flight across this whole iter)
    {
      const u16* Kt = Kbase + (size_t)((it+1 < NIT) ? (k0+32) : k0) * D;
      char* kbn = smem + ((it & 1) ? KB0 : KB1);
#pragma unroll
      for (int c = 0; c < 4; c++)
        gl2lds16(Kt + soff[c], kbn + (wv*4 + c)*1024);
    }
    // prefetch V frags for THIS iter (used after the mid barrier)
    s16x8 vf[4];
#pragma unroll
    for (int nt = 0; nt < 4; nt++)
      vf[nt] = *(const s16x8*)(Vbase + voff[nt] + k0);

    // S = Q K^T (wave's 16 q rows x 32 k cols) from current buffer
    const char* kb = smem + ((it & 1) ? KB1 : KB0);
    f32x4 sa0 = {0.f,0.f,0.f,0.f}, sa1 = {0.f,0.f,0.f,0.f};
    {
      const int r0 = li, r1 = li + 16;
      const char* kp0 = kb + r0*512;
      const char* kp1 = kb + r1*512;
#pragma unroll
      for (int ks = 0; ks < 8; ks++) {
        s16x8 k0f = *(const s16x8*)(kp0 + 16*((4*ks + grp) ^ (r0 & 7)));
        sa0 = __builtin_amdgcn_mfma_f32_16x16x32_bf16(qf[ks], k0f, sa0, 0,0,0);
        s16x8 k1f = *(const s16x8*)(kp1 + 16*((4*ks + grp) ^ (r1 & 7)));
        sa1 = __builtin_amdgcn_mfma_f32_16x16x32_bf16(qf[ks], k1f, sa1, 0,0,0);
      }
    }

    // fixed-max softmax numerator: p = 2^((s - SMAX)*SM_C); no reductions
#pragma unroll
    for (int r = 0; r < 4; r++) {
      float p0 = EXP2F((sa0[r] - SMAX) * SM_C);
      float p1 = EXP2F((sa1[r] - SMAX) * SM_C);
      l_r[r] += p0 + p1;
      int row = 16*wv + grp*4 + r;
      Pl[row*PSTR + li]      = f2bf(p0);
      Pl[row*PSTR + li + 16] = f2bf(p1);
    }
    lgkm_barrier();   // P visible to all waves; K-DMA stays in flight

    // O += P.V (wave's 64-col d strip)
#pragma unroll
    for (int mt = 0; mt < 4; mt++) {
      s16x8 pf = *(const s16x8*)(smem + P_OFF + ((16*mt + li)*PSTR + grp*8)*2);
#pragma unroll
      for (int nt = 0; nt < 4; nt++)
        oacc[mt*4+nt] = __builtin_amdgcn_mfma_f32_16x16x32_bf16(pf, vf[nt], oacc[mt*4+nt], 0,0,0);
    }
  }

  // ------------- epilogue: /l, +residual (f32), LayerNorm, f32 store -------------
  float* l_lds = (float*)(smem + L_OFF);
  {
#pragma unroll
    for (int r = 0; r < 4; r++) {
      float lt = rsum16(l_r[r]);
      if (li == 0) l_lds[16*wv + grp*4 + r] = lt;
    }
  }
  __syncthreads();   // all P reads done -> P region reusable for partials

  const float* Tg = TE + ((size_t)b*SEQ + q0) * D;
  float s1[4][4], s2[4][4];
#pragma unroll
  for (int mt = 0; mt < 4; mt++) {
#pragma unroll
    for (int r = 0; r < 4; r++) {
      int row = 16*mt + grp*4 + r;
      float linv = 1.0f / l_lds[row];
      float ps = 0.f, pq = 0.f;
#pragma unroll
      for (int nt = 0; nt < 4; nt++) {
        int d_ = 64*wv + 16*nt + li;
        float x = oacc[mt*4+nt][r] * linv + Tg[(size_t)row*D + d_];
        oacc[mt*4+nt][r] = x;
        ps += x; pq += x * x;
      }
      s1[mt][r] = rsum16(ps);
      s2[mt][r] = rsum16(pq);
    }
  }
  float* part1 = (float*)(smem + P_OFF);         // [64][4] per-wave partials
  float* part2 = (float*)(smem + P_OFF + 1024);
  if (li == 0) {
#pragma unroll
    for (int mt = 0; mt < 4; mt++)
#pragma unroll
      for (int r = 0; r < 4; r++) {
        int row = 16*mt + grp*4 + r;
        part1[row*4 + wv] = s1[mt][r];
        part2[row*4 + wv] = s2[mt][r];
      }
  }
  __syncthreads();
#pragma unroll
  for (int mt = 0; mt < 4; mt++) {
#pragma unroll
    for (int r = 0; r < 4; r++) {
      int row = 16*mt + grp*4 + r;
      float su = part1[row*4+0] + part1[row*4+1] + part1[row*4+2] + part1[row*4+3];
      float sq = part2[row*4+0] + part2[row*4+1] + part2[row*4+2] + part2[row*4+3];
      float mu  = su * (1.0f/256.0f);
      float var = sq * (1.0f/256.0f) - mu*mu;
      float rstd = rsqrtf(var + 1e-5f);
      float* orow = out + ((size_t)b*SEQ + q0 + row) * D;
#pragma unroll
      for (int nt = 0; nt < 4; nt++) {
        int d_ = 64*wv + 16*nt + li;
        orow[d_] = (oacc[mt*4+nt][r] - mu) * rstd * gam[d_] + bet[d_];
      }
    }
  }
}

// ---------------------------------------------------------------------------
extern "C" void kernel_launch(void* const* d_in, const int* in_sizes, int n_in,
                              void* d_out, int out_size, void* d_ws, size_t ws_size,
                              hipStream_t stream)
{
  (void)in_sizes; (void)n_in; (void)out_size; (void)ws_size;
  const float* SE = (const float*)d_in[0];
  const float* TE = (const float*)d_in[1];
  const float* Wq = (const float*)d_in[2];
  const float* bq = (const float*)d_in[3];
  const float* Wk = (const float*)d_in[4];
  const float* bk = (const float*)d_in[5];
  const float* Wv = (const float*)d_in[6];
  const float* bv = (const float*)d_in[7];
  const float* gm = (const float*)d_in[8];
  const float* bt = (const float*)d_in[9];

  u16* Qb  = (u16*)d_ws;              // 16MB
  u16* Kb  = Qb + N_EMB;              // 16MB
  u16* Vtr = Kb + N_EMB;              // 16MB  [b][d][s]
  u16* CVT = Vtr + N_EMB;             // TEb | SEb | Wqb | Wkb | Wvb
  u16* TEb = CVT;
  u16* SEb = TEb + N_EMB;
  u16* Wqb = SEb + N_EMB;
  u16* Wkb = Wqb + N_W;
  u16* Wvb = Wkb + N_W;

  cvt_all<<<2048, 256, 0, stream>>>(TE, SE, Wq, Wk, Wv, CVT);
  qkv_proj<<<dim3(NTOK/512, 12), 256, 0, stream>>>(TEb, SEb, Wqb, bq, Wkb, bk, Wvb, bv, Qb, Kb, Vtr);
  attn_ln<<<dim3((SEQ/64) * NB), 256, 0, stream>>>(Qb, Kb, Vtr, TE, gm, bt, (float*)d_out);
}